// Round 1
// baseline (44.115 us; speedup 1.0000x reference)
//
#include <hip/hip_runtime.h>
#include <math.h>

#define NTOT 131072
#define NSIG 64
#define SEGL 2048
#define NIN 256

// ws layout (bytes):
//   [0, 524288)        y[131072] f32
//   [524288, 1048576)  w_all[64][2048] f32 (normalized gaussian windows)
//   [1048576, 1048832) Dv[64] int (per-segment effective support)

// ---------------------------------------------------------------------------
// K1: per-segment sigma + gaussian window. 64 blocks x 256 threads.
// Each block redundantly computes s = swish(x@W1+b1) (trivial), reduces its
// own sigma_b = s@W2[:,b]+b2[b], then builds its normalized window row.
// ---------------------------------------------------------------------------
__global__ __launch_bounds__(256) void k_sigma_win(
    const float* __restrict__ x,  const float* __restrict__ W1,
    const float* __restrict__ b1, const float* __restrict__ W2,
    const float* __restrict__ b2, float* __restrict__ w_all,
    int* __restrict__ Dv)
{
  __shared__ float s_lds[256];
  __shared__ float tmp[4];
  __shared__ float sigS, zS;
  const int t = threadIdx.x;
  const int b = blockIdx.x;

  // s[t] = swish(b1[t] + sum_n x[n]*W1[n*256+t])  (coalesced over t)
  float acc = b1[t];
  #pragma unroll 8
  for (int n = 0; n < NIN; ++n) acc += x[n] * W1[n * 256 + t];
  s_lds[t] = acc / (1.0f + expf(-acc));
  __syncthreads();

  // sigma_b = b2[b] + sum_h s[h]*W2[h*64+b]
  float v = s_lds[t] * W2[t * NSIG + b];
  #pragma unroll
  for (int o = 32; o > 0; o >>= 1) v += __shfl_down(v, o, 64);
  const int lane = t & 63, wid = t >> 6;
  if (lane == 0) tmp[wid] = v;
  __syncthreads();
  if (t == 0) sigS = tmp[0] + tmp[1] + tmp[2] + tmp[3] + b2[b];
  __syncthreads();
  const float sig = sigS;

  // window: e[ti] = exp(-(ti-1024)^2 / (2 sig^2)); Z = sum over all 2048 taps
  const float inv2 = 1.0f / (2.0f * sig * sig);
  float e[8];
  float zp = 0.0f;
  #pragma unroll
  for (int j = 0; j < 8; ++j) {
    const float d = (float)(t + j * 256 - 1024);
    e[j] = expf(-d * d * inv2);
    zp += e[j];
  }
  v = zp;
  #pragma unroll
  for (int o = 32; o > 0; o >>= 1) v += __shfl_down(v, o, 64);
  if (lane == 0) tmp[wid] = v;
  __syncthreads();
  if (t == 0) zS = tmp[0] + tmp[1] + tmp[2] + tmp[3];
  __syncthreads();
  const float Z = zS;

  #pragma unroll
  for (int j = 0; j < 8; ++j)
    w_all[b * SEGL + t + j * 256] = e[j] / Z;

  // effective support: taps beyond 12|sigma|+4 are exp(<-72) == 0 in f32
  if (t == 0) {
    float Df = 12.0f * fabsf(sig) + 4.0f;
    int D = (Df >= 1024.0f) ? 1024 : (int)Df;
    Dv[b] = D;
  }
}

// ---------------------------------------------------------------------------
// K2: y = x @ W3 + b3. The HBM-bound kernel (134 MB of W3, read once).
// 256 blocks x 256 threads, 2 columns/thread (float2, 8B/lane coalesced).
// ---------------------------------------------------------------------------
__global__ __launch_bounds__(256) void k_matvec(
    const float* __restrict__ x, const float* __restrict__ W3,
    const float* __restrict__ b3, float* __restrict__ y)
{
  const int col = (blockIdx.x * 256 + threadIdx.x) * 2;
  const float* wp = W3 + col;
  float ax = b3[col];
  float ay = b3[col + 1];
  #pragma unroll 16
  for (int n = 0; n < NIN; ++n) {
    const float xv = x[n];  // uniform -> s_load broadcast
    const float2 wv = *reinterpret_cast<const float2*>(wp + (size_t)n * NTOT);
    ax += xv * wv.x;
    ay += xv * wv.y;
  }
  *reinterpret_cast<float2*>(y + col) = make_float2(ax, ay);
}

// ---------------------------------------------------------------------------
// K3: truncated "same" convolution per segment.
// out[m] = sum_d w[1024+d] * seg[m-1-d],  d in [-min(D,1024), min(D,1023)]
// 256 blocks (4 per segment) x 256 threads; each block does 512 outputs.
// Zero-padded segment slice + window row staged in LDS.
// ---------------------------------------------------------------------------
__global__ __launch_bounds__(256) void k_conv(
    const float* __restrict__ y, const float* __restrict__ w_all,
    const int* __restrict__ Dv, float* __restrict__ out)
{
  __shared__ float S[2560];   // padded seg slice: seg[M0-1025 .. M0+1534]
  __shared__ float Wl[SEGL];  // window row
  const int t = threadIdx.x;
  const int bx = blockIdx.x;
  const int seg = bx >> 2;
  const int M0 = (bx & 3) * 512;
  const int base = M0 - 1025;

  #pragma unroll
  for (int j = 0; j < 10; ++j) {
    const int i = t + j * 256;
    const int g = base + i;
    float v = 0.0f;
    if (g >= 0 && g < SEGL) v = y[seg * SEGL + g];
    S[i] = v;
  }
  #pragma unroll
  for (int j = 0; j < 8; ++j) {
    const int i = t + j * 256;
    Wl[i] = w_all[seg * SEGL + i];
  }
  __syncthreads();

  const int D = Dv[seg];
  const int dlo = -((D < 1024) ? D : 1024);
  const int dhi = (D < 1023) ? D : 1023;

  float a0 = 0.0f, a1 = 0.0f;
  for (int d = dlo; d <= dhi; ++d) {
    const float wd = Wl[1024 + d];          // uniform -> broadcast
    a0 += wd * S[t + 1024 - d];             // stride-1 across lanes
    a1 += wd * S[t + 1280 - d];
  }
  const int ob = seg * SEGL + M0 + t;
  out[ob] = a0;
  out[ob + 256] = a1;
}

// ---------------------------------------------------------------------------
extern "C" void kernel_launch(void* const* d_in, const int* in_sizes, int n_in,
                              void* d_out, int out_size, void* d_ws, size_t ws_size,
                              hipStream_t stream) {
  const float* x  = (const float*)d_in[0];
  const float* W1 = (const float*)d_in[1];
  const float* b1 = (const float*)d_in[2];
  const float* W2 = (const float*)d_in[3];
  const float* b2 = (const float*)d_in[4];
  const float* W3 = (const float*)d_in[5];
  const float* b3 = (const float*)d_in[6];
  float* out = (float*)d_out;

  char* ws = (char*)d_ws;
  float* y     = (float*)(ws);
  float* w_all = (float*)(ws + 524288);
  int*   Dv    = (int*)  (ws + 1048576);

  hipLaunchKernelGGL(k_sigma_win, dim3(NSIG), dim3(256), 0, stream,
                     x, W1, b1, W2, b2, w_all, Dv);
  hipLaunchKernelGGL(k_matvec, dim3(NTOT / 512), dim3(256), 0, stream,
                     x, W3, b3, y);
  hipLaunchKernelGGL(k_conv, dim3(NSIG * 4), dim3(256), 0, stream,
                     y, w_all, Dv, out);
}

// Round 2
// 39.866 us; speedup vs baseline: 1.1066x; 1.1066x over previous
//
#include <hip/hip_runtime.h>
#include <math.h>

#define NTOT 131072
#define NSIG 64
#define SEGL 2048
#define NIN 256

// One fused kernel. 256 blocks x 256 threads; block handles 512 outputs
// (seg = bx>>2, chunk M0 = (bx&3)*512).
// Phases: [zero S] -> MLP sigma (redundant per block, tiny) -> window in LDS
//         -> truncated-range matvec (core 512 cols + 2D halo) into LDS
//         -> truncated conv -> store.
// Truncation: gaussian taps beyond |d| = 12|sigma|+4 are exp(<-72) == 0 in f32,
// and Z >= 1 (peak tap is exp(0)), so truncation error is identically 0 in f32.
__global__ __launch_bounds__(256) void k_fused(
    const float* __restrict__ x,  const float* __restrict__ W1,
    const float* __restrict__ b1, const float* __restrict__ W2,
    const float* __restrict__ b2, const float* __restrict__ W3,
    const float* __restrict__ b3, float* __restrict__ out)
{
  __shared__ float xl[NIN];     // x staged
  __shared__ float sl[256];     // swish hidden
  __shared__ float red[4];
  __shared__ float bc[2];       // sigma, Z
  __shared__ float S[2816];     // y slice, base = M0-1026, valid span 2562
  __shared__ float Wl[SEGL];    // normalized window

  const int t = threadIdx.x;
  // bijective XCD swizzle: 256 blocks, 8 XCDs -> 32 consecutive chunks per XCD
  const int bx0 = (int)blockIdx.x;
  const int bx = ((bx0 & 7) << 5) | (bx0 >> 3);
  const int seg = bx >> 2;
  const int M0 = (bx & 3) * 512;

  // zero-init padded y slice (zero padding == "same" conv boundary)
  #pragma unroll
  for (int j = 0; j < 11; ++j) S[t + j * 256] = 0.0f;
  xl[t] = x[t];
  __syncthreads();

  // ---- MLP: s = swish(x@W1 + b1); hidden unit t per thread ----
  float acc = b1[t];
  #pragma unroll 16
  for (int n = 0; n < NIN; ++n) acc += xl[n] * W1[n * 256 + t];
  sl[t] = acc / (1.0f + expf(-acc));
  __syncthreads();

  // ---- sigma_seg = s @ W2[:,seg] + b2[seg] ----
  float v = sl[t] * W2[t * NSIG + seg];
  #pragma unroll
  for (int o = 32; o > 0; o >>= 1) v += __shfl_down(v, o, 64);
  const int lane = t & 63, wid = t >> 6;
  if (lane == 0) red[wid] = v;
  __syncthreads();
  if (t == 0) bc[0] = red[0] + red[1] + red[2] + red[3] + b2[seg];
  __syncthreads();
  const float sig = bc[0];

  // ---- gaussian window + normalizer ----
  const float inv2 = 1.0f / (2.0f * sig * sig);
  float e[8];
  float zp = 0.0f;
  #pragma unroll
  for (int j = 0; j < 8; ++j) {
    const float d = (float)(t + j * 256 - 1024);
    e[j] = expf(-d * d * inv2);
    zp += e[j];
  }
  v = zp;
  #pragma unroll
  for (int o = 32; o > 0; o >>= 1) v += __shfl_down(v, o, 64);
  if (lane == 0) red[wid] = v;
  __syncthreads();
  if (t == 0) bc[1] = red[0] + red[1] + red[2] + red[3];
  __syncthreads();
  const float iZ = 1.0f / bc[1];
  #pragma unroll
  for (int j = 0; j < 8; ++j) Wl[t + j * 256] = e[j] * iZ;

  const float Df = 12.0f * fabsf(sig) + 4.0f;
  const int D = (Df >= 1024.0f) ? 1024 : (int)Df;

  // ---- truncated matvec: y cols [clo, chi) of this segment ----
  int clo = M0 - 1 - D; if (clo < 0) clo = 0;
  int chi = M0 + 512 + D; if (chi > SEGL) chi = SEGL;
  clo &= ~1;                    // float2 alignment (stays >= 0)
  chi = (chi + 1) & ~1;         // SEGL even, so stays <= SEGL
  const int ng = (((chi - clo) >> 1) + 255) >> 8;
  const int segbase = seg * SEGL;
  const int sbase = M0 - 1026;  // S[] base in segment coords

  for (int g = 0; g < ng; ++g) {
    const int c = clo + ((g << 8) + t) * 2;
    if (c < chi) {
      const float* wp = W3 + segbase + c;
      float ax = b3[segbase + c];
      float ay = b3[segbase + c + 1];
      #pragma unroll 16
      for (int n = 0; n < NIN; ++n) {
        const float xv = xl[n];
        const float2 wv = *reinterpret_cast<const float2*>(wp + (size_t)n * NTOT);
        ax += xv * wv.x;
        ay += xv * wv.y;
      }
      const int si = c - sbase;
      S[si] = ax;
      S[si + 1] = ay;
    }
  }
  __syncthreads();

  // ---- truncated conv: out[m] = sum_d Wl[1024+d] * seg[m-1-d] ----
  const int dlo = -((D < 1024) ? D : 1024);
  const int dhi = (D < 1023) ? D : 1023;
  float a0 = 0.0f, a1 = 0.0f;
  for (int d = dlo; d <= dhi; ++d) {
    const float wd = Wl[1024 + d];      // uniform broadcast
    a0 += wd * S[t + 1025 - d];         // stride-1 across lanes
    a1 += wd * S[t + 1281 - d];
  }
  const int ob = segbase + M0 + t;
  out[ob] = a0;
  out[ob + 256] = a1;
}

extern "C" void kernel_launch(void* const* d_in, const int* in_sizes, int n_in,
                              void* d_out, int out_size, void* d_ws, size_t ws_size,
                              hipStream_t stream) {
  const float* x  = (const float*)d_in[0];
  const float* W1 = (const float*)d_in[1];
  const float* b1 = (const float*)d_in[2];
  const float* W2 = (const float*)d_in[3];
  const float* b2 = (const float*)d_in[4];
  const float* W3 = (const float*)d_in[5];
  const float* b3 = (const float*)d_in[6];
  float* out = (float*)d_out;

  hipLaunchKernelGGL(k_fused, dim3(256), dim3(256), 0, stream,
                     x, W1, b1, W2, b2, W3, b3, out);
}